// Round 2
// baseline (659.842 us; speedup 1.0000x reference)
//
#include <hip/hip_runtime.h>

// Problem constants
#define B_SZ 512
#define C_CH 256
#define L_SEQ 256
#define H_DIM 512
#define T_STEP 16
#define W_WIN 8
#define NSLAB 24   // max distinct l values = T+W-1 = 23, round up

typedef __attribute__((ext_vector_type(8))) short short8;
typedef __attribute__((ext_vector_type(4))) float f32x4;

#define GLOBAL_U32 const __attribute__((address_space(1))) unsigned int*
#define LDS_U32 __attribute__((address_space(3))) unsigned int*
// async 16B/lane global->LDS; LDS dest = wave-uniform base + lane*16
#define ASYNC_COPY16(g, l) \
  __builtin_amdgcn_global_load_lds((GLOBAL_U32)(const void*)(g), (LDS_U32)(void*)(l), 16, 0, 0)

__device__ inline unsigned short f2bf(float x) {  // RNE f32 -> bf16
  unsigned u = __float_as_uint(x);
  u = (u + 0x7FFFu + ((u >> 16) & 1u)) >> 16;
  return (unsigned short)u;
}

// ---------------- cast f32 -> bf16 (4 elems/thread) ----------------
__global__ void cast_bf(const float* __restrict__ s, unsigned short* __restrict__ d, int n) {
  int i = (blockIdx.x * 256 + threadIdx.x) * 4;
  if (i < n) {
    float4 v = ((const float4*)s)[i >> 2];
    ushort4 o;
    o.x = f2bf(v.x); o.y = f2bf(v.y); o.z = f2bf(v.z); o.w = f2bf(v.w);
    ((ushort4*)d)[i >> 2] = o;
  }
}

// ---------------- encode slabs: F[l'][b][c] = bf16(features[b][c][lmin+l']) ----------------
// grid 64 x 256: 8 b's x 32 lanes (lanes cover l' -> coalesced reads along L)
__global__ void build_slabs(const float* __restrict__ f, unsigned short* __restrict__ F,
                            const int* __restrict__ tsp) {
  int ts = tsp[0];
  int lmin = min(ts + 1, L_SEQ - W_WIN);
  int b = blockIdx.x * 8 + (threadIdx.x >> 5);
  int lp = threadIdx.x & 31;
  if (lp >= NSLAB) return;
  int l = lmin + lp;
  bool ok = (l < L_SEQ);
  for (int c = 0; c < C_CH; c++) {
    float v = ok ? f[((size_t)b * C_CH + c) * L_SEQ + l] : 0.f;
    F[((size_t)lp * B_SZ + b) * C_CH + c] = f2bf(v);
  }
}

// ---------------- bf16 MFMA GEMM: D = A[M,K] * Bt[N,K]^T + bias[col] ----------------
// MODE 0: out = pred bf16, remapped to [t][w][a][c]  (row bw -> (a,w), col tc -> (t,c))
// MODE 1: out = f32 row-major [M][128] (h1 pre-BN)
template <int MODE>
__global__ __launch_bounds__(256) void gemm_bt(const unsigned short* __restrict__ A,
                                               const unsigned short* __restrict__ Bt,
                                               const float* __restrict__ bias,
                                               unsigned short* __restrict__ outb,
                                               float* __restrict__ outf, int K) {
  __shared__ __align__(16) unsigned short As[128 * 64];
  __shared__ __align__(16) unsigned short Bs[128 * 64];
  const int tid = threadIdx.x;
  const int wv = tid >> 6, lane = tid & 63, quad = lane >> 4, l15 = lane & 15;
  const int wm = wv >> 1, wn = wv & 1;
  const int M0 = blockIdx.x * 128, N0 = blockIdx.y * 128;

  f32x4 acc[4][4];
#pragma unroll
  for (int i = 0; i < 4; i++)
#pragma unroll
    for (int j = 0; j < 4; j++) acc[i][j] = (f32x4){0.f, 0.f, 0.f, 0.f};

  for (int k0 = 0; k0 < K; k0 += 64) {
#pragma unroll
    for (int i = 0; i < 4; i++) {
      int chunk = (i * 4 + wv) * 64 + lane;      // 1024 chunks of 16B = [128][64] bf16 tile
      int row = chunk >> 3, off = chunk & 7;     // 8 chunks per 128B row
      const unsigned short* ga = A + (size_t)(M0 + row) * K + k0 + off * 8;
      const unsigned short* gb = Bt + (size_t)(N0 + row) * K + k0 + off * 8;
      ASYNC_COPY16(ga, &As[(size_t)(i * 4 + wv) * 512]);
      ASYNC_COPY16(gb, &Bs[(size_t)(i * 4 + wv) * 512]);
    }
    __syncthreads();  // drains vmcnt
#pragma unroll
    for (int kk = 0; kk < 64; kk += 32) {
      short8 af[4], bfr[4];
#pragma unroll
      for (int i = 0; i < 4; i++)
        af[i] = *(const short8*)&As[(wm * 64 + i * 16 + l15) * 64 + kk + quad * 8];
#pragma unroll
      for (int j = 0; j < 4; j++)
        bfr[j] = *(const short8*)&Bs[(wn * 64 + j * 16 + l15) * 64 + kk + quad * 8];
#pragma unroll
      for (int i = 0; i < 4; i++)
#pragma unroll
        for (int j = 0; j < 4; j++)
          acc[i][j] = __builtin_amdgcn_mfma_f32_16x16x32_bf16(af[i], bfr[j], acc[i][j], 0, 0, 0);
    }
    __syncthreads();
  }

  // epilogue: D mapping col=lane&15, row=quad*4+reg (m89/m91-verified)
#pragma unroll
  for (int i = 0; i < 4; i++) {
    int rbase = M0 + wm * 64 + i * 16 + quad * 4;
#pragma unroll
    for (int j = 0; j < 4; j++) {
      int cc = N0 + wn * 64 + j * 16 + l15;
      float bv = bias[cc];
#pragma unroll
      for (int r = 0; r < 4; r++) {
        int rr = rbase + r;
        float v = acc[i][j][r] + bv;
        if (MODE == 0) {
          int t = cc >> 8, c = cc & 255, a = rr >> 3, w_ = rr & 7;
          outb[((size_t)(t * 8 + w_) * 512 + a) * 256 + c] = f2bf(v);
        } else {
          outf[(size_t)rr * 128 + cc] = v;
        }
      }
    }
  }
}

// ---------------- fused scores + log-softmax-diag NCE partial ----------------
// block: one (t,w) batch, 32 E-rows (b), full 512 cols (a). 4 waves x 128 cols.
__global__ __launch_bounds__(256) void scores_nce(const unsigned short* __restrict__ F,
                                                  const unsigned short* __restrict__ pred,
                                                  const int* __restrict__ tsp,
                                                  float* __restrict__ partials) {
  __shared__ __align__(16) unsigned short Es[32 * 32];
  __shared__ __align__(16) unsigned short Ps[512 * 32];
  __shared__ float red[4][32];
  __shared__ float rowmax[32];
  __shared__ float diagv[32];
  __shared__ float rowpart[32];

  const int tid = threadIdx.x;
  const int wv = tid >> 6, lane = tid & 63, quad = lane >> 4, l15 = lane & 15;
  const int tw = blockIdx.x;
  const int b0 = blockIdx.y * 32;
  const int t = tw >> 3, w_ = tw & 7;
  const int ts = tsp[0];
  const int lmin = min(ts + 1, L_SEQ - W_WIN);
  const int lp = min(ts + 1 + t, L_SEQ - W_WIN) + w_ - lmin;
  const unsigned short* E = F + (size_t)lp * B_SZ * C_CH;
  const unsigned short* P = pred + (size_t)tw * B_SZ * C_CH;

  f32x4 acc[2][8];
#pragma unroll
  for (int i = 0; i < 2; i++)
#pragma unroll
    for (int j = 0; j < 8; j++) acc[i][j] = (f32x4){0.f, 0.f, 0.f, 0.f};

  for (int k0 = 0; k0 < C_CH; k0 += 32) {
    if (wv < 2) {  // Es: 32x32 bf16 = 2KB = 128 chunks -> waves 0,1
      int chunk = wv * 64 + lane;
      int row = chunk >> 2, off = chunk & 3;  // 4 chunks per 64B row
      ASYNC_COPY16(E + (size_t)(b0 + row) * C_CH + k0 + off * 8, &Es[(size_t)wv * 512]);
    }
#pragma unroll
    for (int i = 0; i < 8; i++) {  // Ps: 512x32 bf16 = 32KB = 2048 chunks
      int chunk = (i * 4 + wv) * 64 + lane;
      int row = chunk >> 2, off = chunk & 3;
      ASYNC_COPY16(P + (size_t)row * C_CH + k0 + off * 8, &Ps[(size_t)(i * 4 + wv) * 512]);
    }
    __syncthreads();
    short8 af0 = *(const short8*)&Es[(l15)*32 + quad * 8];
    short8 af1 = *(const short8*)&Es[(16 + l15) * 32 + quad * 8];
#pragma unroll
    for (int cg = 0; cg < 8; cg++) {
      short8 bfr = *(const short8*)&Ps[((size_t)wv * 128 + cg * 16 + l15) * 32 + quad * 8];
      acc[0][cg] = __builtin_amdgcn_mfma_f32_16x16x32_bf16(af0, bfr, acc[0][cg], 0, 0, 0);
      acc[1][cg] = __builtin_amdgcn_mfma_f32_16x16x32_bf16(af1, bfr, acc[1][cg], 0, 0, 0);
    }
    __syncthreads();
  }

  // ---- per-row (b) max over 512 cols ----
  float pm[2][4];
#pragma unroll
  for (int rg = 0; rg < 2; rg++)
#pragma unroll
    for (int r = 0; r < 4; r++) {
      float m = -1e30f;
#pragma unroll
      for (int cg = 0; cg < 8; cg++) m = fmaxf(m, acc[rg][cg][r]);
      pm[rg][r] = m;
    }
  for (int d = 1; d < 16; d <<= 1)
#pragma unroll
    for (int rg = 0; rg < 2; rg++)
#pragma unroll
      for (int r = 0; r < 4; r++) pm[rg][r] = fmaxf(pm[rg][r], __shfl_xor(pm[rg][r], d));
  if (l15 == 0)
#pragma unroll
    for (int rg = 0; rg < 2; rg++)
#pragma unroll
      for (int r = 0; r < 4; r++) red[wv][rg * 16 + quad * 4 + r] = pm[rg][r];
  __syncthreads();
  if (tid < 32)
    rowmax[tid] = fmaxf(fmaxf(red[0][tid], red[1][tid]), fmaxf(red[2][tid], red[3][tid]));
  __syncthreads();

  // ---- sum of exp ----
  float rm[2][4], ps[2][4];
#pragma unroll
  for (int rg = 0; rg < 2; rg++)
#pragma unroll
    for (int r = 0; r < 4; r++) {
      rm[rg][r] = rowmax[rg * 16 + quad * 4 + r];
      ps[rg][r] = 0.f;
    }
#pragma unroll
  for (int rg = 0; rg < 2; rg++)
#pragma unroll
    for (int cg = 0; cg < 8; cg++)
#pragma unroll
      for (int r = 0; r < 4; r++) ps[rg][r] += __expf(acc[rg][cg][r] - rm[rg][r]);
  for (int d = 1; d < 16; d <<= 1)
#pragma unroll
    for (int rg = 0; rg < 2; rg++)
#pragma unroll
      for (int r = 0; r < 4; r++) ps[rg][r] += __shfl_xor(ps[rg][r], d);
  if (l15 == 0)
#pragma unroll
    for (int rg = 0; rg < 2; rg++)
#pragma unroll
      for (int r = 0; r < 4; r++) red[wv][rg * 16 + quad * 4 + r] = ps[rg][r];

  // ---- diagonal: col a == global row b ----
#pragma unroll
  for (int rg = 0; rg < 2; rg++)
#pragma unroll
    for (int r = 0; r < 4; r++) {
      int row = rg * 16 + quad * 4 + r;
      int gb = b0 + row;
      if (wv == (gb >> 7) && l15 == (gb & 15)) {
        int cg = (gb >> 4) & 7;
        diagv[row] = acc[rg][cg][r];
      }
    }
  __syncthreads();
  if (tid < 32) {
    float s = red[0][tid] + red[1][tid] + red[2][tid] + red[3][tid];
    rowpart[tid] = rowmax[tid] + __logf(s) - diagv[tid];  // lse - diag = -logp[b,b]
  }
  __syncthreads();
  if (tid == 0) {
    float s = 0.f;
    for (int i = 0; i < 32; i++) s += rowpart[i];
    partials[blockIdx.y * gridDim.x + blockIdx.x] = s;
  }
}

__global__ void nce_finish(const float* __restrict__ partials, float* __restrict__ out) {
  __shared__ float r[256];
  float s = 0.f;
  for (int i = threadIdx.x; i < 2048; i += 256) s += partials[i];
  r[threadIdx.x] = s;
  __syncthreads();
  if (threadIdx.x == 0) {
    float tsum = 0.f;
    for (int i = 0; i < 256; i++) tsum += r[i];
    // partials already hold Σ(lse - diag) = Σ(-logp_diag); nce = +Σ/N
    out[0] = tsum / 65536.0f;  // B*T*W
  }
}

// ---------------- BN train stats (two stage, fp32) ----------------
__global__ void bn_stage1(const float* __restrict__ h1, float* __restrict__ p1,
                          float* __restrict__ p2) {
  int c = threadIdx.x;  // 128 threads
  int blk = blockIdx.x; // 32 blocks x 128 rows
  float s1 = 0.f, s2 = 0.f;
  for (int r = blk * 128; r < blk * 128 + 128; r++) {
    float v = h1[(size_t)r * 128 + c];
    s1 += v;
    s2 += v * v;
  }
  p1[blk * 128 + c] = s1;
  p2[blk * 128 + c] = s2;
}

__global__ void bn_stage2(const float* __restrict__ p1, const float* __restrict__ p2,
                          const float* __restrict__ g, const float* __restrict__ b,
                          float* __restrict__ sc, float* __restrict__ sh) {
  int c = threadIdx.x;
  float s1 = 0.f, s2 = 0.f;
  for (int k = 0; k < 32; k++) {
    s1 += p1[k * 128 + c];
    s2 += p2[k * 128 + c];
  }
  float mean = s1 * (1.f / 4096.f);
  float var = s2 * (1.f / 4096.f) - mean * mean;  // biased (BN train)
  float scale = g[c] * rsqrtf(var + 1e-5f);
  sc[c] = scale;
  sh[c] = b[c] - mean * scale;
}

// ---------------- BN-apply + ReLU + GEMM2 -> proj (fp32) ----------------
__global__ __launch_bounds__(256) void proj_gemm2(const float* __restrict__ h1,
                                                  const float* __restrict__ sc,
                                                  const float* __restrict__ sh,
                                                  const float* __restrict__ pw2,
                                                  const float* __restrict__ pb2,
                                                  float* __restrict__ out) {
  __shared__ float pw2s[64][129];  // +1 pad breaks bank aliasing
  __shared__ float hs[16][129];
  __shared__ float scs[128], shs[128];
  int tid = threadIdx.x;
  for (int idx = tid; idx < 64 * 128; idx += 256) pw2s[idx >> 7][idx & 127] = pw2[idx];
  if (tid < 128) { scs[tid] = sc[tid]; shs[tid] = sh[tid]; }
  __syncthreads();
  int r0 = blockIdx.x * 64;
  float bb = pb2[tid & 63];
  for (int ch = 0; ch < 4; ch++) {
    int rr0 = r0 + ch * 16;
    for (int idx = tid; idx < 16 * 128; idx += 256) {
      int r = idx >> 7, c = idx & 127;
      float v = h1[(size_t)(rr0 + r) * 128 + c];
      hs[r][c] = fmaxf(v * scs[c] + shs[c], 0.f);
    }
    __syncthreads();
    int oc = tid & 63, og = tid >> 6;
#pragma unroll
    for (int q = 0; q < 4; q++) {
      int row = og * 4 + q;
      float s = bb;
      for (int c = 0; c < 128; c++) s += hs[row][c] * pw2s[oc][c];
      out[(size_t)(rr0 + row) * 64 + oc] = s;
    }
    __syncthreads();
  }
}

extern "C" void kernel_launch(void* const* d_in, const int* in_sizes, int n_in,
                              void* d_out, int out_size, void* d_ws, size_t ws_size,
                              hipStream_t stream) {
  const float* features = (const float*)d_in[0];
  const float* c_t      = (const float*)d_in[1];
  const float* Wk_w     = (const float*)d_in[2];
  const float* Wk_b     = (const float*)d_in[3];
  const float* pw1      = (const float*)d_in[4];
  const float* pb1      = (const float*)d_in[5];
  const float* bn_gamma = (const float*)d_in[6];
  const float* bn_beta  = (const float*)d_in[7];
  const float* pw2      = (const float*)d_in[8];
  const float* pb2      = (const float*)d_in[9];
  const int*   tsp      = (const int*)d_in[10];
  float* out = (float*)d_out;

  // workspace carve-up (~48.2 MB total)
  char* ws = (char*)d_ws;
  size_t off = 0;
  auto carve = [&](size_t bytes) { void* p = ws + off; off += (bytes + 255) & ~(size_t)255; return p; };
  unsigned short* ct_bf  = (unsigned short*)carve((size_t)4096 * 512 * 2);   // c_t bf16 [bw][h]
  unsigned short* wk_bf  = (unsigned short*)carve((size_t)4096 * 512 * 2);   // Wk bf16 [tc][h]
  unsigned short* pw1_bf = (unsigned short*)carve((size_t)128 * 512 * 2);
  unsigned short* F      = (unsigned short*)carve((size_t)NSLAB * 512 * 256 * 2);
  unsigned short* pred   = (unsigned short*)carve((size_t)16 * 8 * 512 * 256 * 2);
  float* h1    = (float*)carve((size_t)4096 * 128 * 4);
  float* bnp1  = (float*)carve((size_t)32 * 128 * 4);
  float* bnp2  = (float*)carve((size_t)32 * 128 * 4);
  float* bnsc  = (float*)carve((size_t)128 * 4);
  float* bnsh  = (float*)carve((size_t)128 * 4);
  float* parts = (float*)carve((size_t)2048 * 4);

  cast_bf<<<2048, 256, 0, stream>>>(c_t, ct_bf, 4096 * 512);
  cast_bf<<<2048, 256, 0, stream>>>(Wk_w, wk_bf, 4096 * 512);
  cast_bf<<<64, 256, 0, stream>>>(pw1, pw1_bf, 128 * 512);
  build_slabs<<<64, 256, 0, stream>>>(features, F, tsp);

  // pred[t][w][a][c] = c_t @ Wk^T + Wk_b   (M=N=4096, K=512)
  gemm_bt<0><<<dim3(32, 32), 256, 0, stream>>>(ct_bf, wk_bf, Wk_b, pred, nullptr, 512);
  // h1 = c_t2d @ pw1^T + pb1   (M=4096, N=128, K=512)
  gemm_bt<1><<<dim3(32, 1), 256, 0, stream>>>(ct_bf, pw1_bf, pb1, nullptr, h1, 512);

  scores_nce<<<dim3(128, 16), 256, 0, stream>>>(F, pred, tsp, parts);
  nce_finish<<<1, 256, 0, stream>>>(parts, out);

  bn_stage1<<<32, 128, 0, stream>>>(h1, bnp1, bnp2);
  bn_stage2<<<1, 128, 0, stream>>>(bnp1, bnp2, bn_gamma, bn_beta, bnsc, bnsh);
  proj_gemm2<<<64, 256, 0, stream>>>(h1, bnsc, bnsh, pw2, pb2, out + 1);
}

// Round 3
// 486.740 us; speedup vs baseline: 1.3556x; 1.3556x over previous
//
#include <hip/hip_runtime.h>

// Problem constants
#define B_SZ 512
#define C_CH 256
#define L_SEQ 256
#define H_DIM 512
#define T_STEP 16
#define W_WIN 8
#define NSLAB 24   // max distinct l values = T+W-1 = 23, round up

typedef __attribute__((ext_vector_type(8))) short short8;
typedef __attribute__((ext_vector_type(4))) float f32x4;

#define GLOBAL_U32 const __attribute__((address_space(1))) unsigned int*
#define LDS_U32 __attribute__((address_space(3))) unsigned int*
// async 16B/lane global->LDS; LDS dest = wave-uniform base + lane*16
#define ASYNC_COPY16(g, l) \
  __builtin_amdgcn_global_load_lds((GLOBAL_U32)(const void*)(g), (LDS_U32)(void*)(l), 16, 0, 0)

__device__ inline unsigned short f2bf(float x) {  // RNE f32 -> bf16
  unsigned u = __float_as_uint(x);
  u = (u + 0x7FFFu + ((u >> 16) & 1u)) >> 16;
  return (unsigned short)u;
}

// ---------------- cast f32 -> bf16 (4 elems/thread) ----------------
__global__ void cast_bf(const float* __restrict__ s, unsigned short* __restrict__ d, int n) {
  int i = (blockIdx.x * 256 + threadIdx.x) * 4;
  if (i < n) {
    float4 v = ((const float4*)s)[i >> 2];
    ushort4 o;
    o.x = f2bf(v.x); o.y = f2bf(v.y); o.z = f2bf(v.z); o.w = f2bf(v.w);
    ((ushort4*)d)[i >> 2] = o;
  }
}

// ---------------- encode slabs: F[l'][b][c] = bf16(features[b][c][lmin+l']) ----------------
__global__ void build_slabs(const float* __restrict__ f, unsigned short* __restrict__ F,
                            const int* __restrict__ tsp) {
  int ts = tsp[0];
  int lmin = min(ts + 1, L_SEQ - W_WIN);
  int b = blockIdx.x * 8 + (threadIdx.x >> 5);
  int lp = threadIdx.x & 31;
  if (lp >= NSLAB) return;
  int l = lmin + lp;
  bool ok = (l < L_SEQ);
  for (int c = 0; c < C_CH; c++) {
    float v = ok ? f[((size_t)b * C_CH + c) * L_SEQ + l] : 0.f;
    F[((size_t)lp * B_SZ + b) * C_CH + c] = f2bf(v);
  }
}

// ---------------- bf16 MFMA GEMM: D = A[M,K] * Bt[N,K]^T + bias[col] ----------------
template <int MODE>
__global__ __launch_bounds__(256) void gemm_bt(const unsigned short* __restrict__ A,
                                               const unsigned short* __restrict__ Bt,
                                               const float* __restrict__ bias,
                                               unsigned short* __restrict__ outb,
                                               float* __restrict__ outf, int K) {
  __shared__ __align__(16) unsigned short As[128 * 64];
  __shared__ __align__(16) unsigned short Bs[128 * 64];
  const int tid = threadIdx.x;
  const int wv = tid >> 6, lane = tid & 63, quad = lane >> 4, l15 = lane & 15;
  const int wm = wv >> 1, wn = wv & 1;
  const int M0 = blockIdx.x * 128, N0 = blockIdx.y * 128;

  f32x4 acc[4][4];
#pragma unroll
  for (int i = 0; i < 4; i++)
#pragma unroll
    for (int j = 0; j < 4; j++) acc[i][j] = (f32x4){0.f, 0.f, 0.f, 0.f};

  for (int k0 = 0; k0 < K; k0 += 64) {
#pragma unroll
    for (int i = 0; i < 4; i++) {
      int chunk = (i * 4 + wv) * 64 + lane;      // 1024 chunks of 16B = [128][64] bf16 tile
      int row = chunk >> 3, off = chunk & 7;     // 8 chunks per 128B row
      const unsigned short* ga = A + (size_t)(M0 + row) * K + k0 + off * 8;
      const unsigned short* gb = Bt + (size_t)(N0 + row) * K + k0 + off * 8;
      ASYNC_COPY16(ga, &As[(size_t)(i * 4 + wv) * 512]);
      ASYNC_COPY16(gb, &Bs[(size_t)(i * 4 + wv) * 512]);
    }
    __syncthreads();  // drains vmcnt
#pragma unroll
    for (int kk = 0; kk < 64; kk += 32) {
      short8 af[4], bfr[4];
#pragma unroll
      for (int i = 0; i < 4; i++)
        af[i] = *(const short8*)&As[(wm * 64 + i * 16 + l15) * 64 + kk + quad * 8];
#pragma unroll
      for (int j = 0; j < 4; j++)
        bfr[j] = *(const short8*)&Bs[(wn * 64 + j * 16 + l15) * 64 + kk + quad * 8];
#pragma unroll
      for (int i = 0; i < 4; i++)
#pragma unroll
        for (int j = 0; j < 4; j++)
          acc[i][j] = __builtin_amdgcn_mfma_f32_16x16x32_bf16(af[i], bfr[j], acc[i][j], 0, 0, 0);
    }
    __syncthreads();
  }

  // epilogue: D mapping col=lane&15, row=quad*4+reg (m89/m91-verified)
#pragma unroll
  for (int i = 0; i < 4; i++) {
    int rbase = M0 + wm * 64 + i * 16 + quad * 4;
#pragma unroll
    for (int j = 0; j < 4; j++) {
      int cc = N0 + wn * 64 + j * 16 + l15;
      float bv = bias[cc];
#pragma unroll
      for (int r = 0; r < 4; r++) {
        int rr = rbase + r;
        float v = acc[i][j][r] + bv;
        if (MODE == 0) {
          int t = cc >> 8, c = cc & 255, a = rr >> 3, w_ = rr & 7;
          outb[((size_t)(t * 8 + w_) * 512 + a) * 256 + c] = f2bf(v);
        } else {
          outf[(size_t)rr * 128 + cc] = v;
        }
      }
    }
  }
}

// ---------------- scores + fixed-shift logsumexp + diag, barrier-free streaming ----------------
// grid (4 b-chunks, 128 tw). Block: 128 b-rows x all 512 a-cols. Wave: 32 rows (2 tiles).
// A-frags (E) register-resident for full K=256; B-frags (P) streamed global->VGPR,
// double-buffered, NO LDS / NO __syncthreads in the loop (fine-grained vmcnt survives).
#define NCE_SHIFT 40.0f
__global__ __launch_bounds__(256, 2) void scores_nce2(const unsigned short* __restrict__ F,
                                                      const unsigned short* __restrict__ pred,
                                                      const int* __restrict__ tsp,
                                                      float* __restrict__ partials) {
  const int tid = threadIdx.x;
  const int wv = tid >> 6, lane = tid & 63, quad = lane >> 4, l15 = lane & 15;
  const int bq = blockIdx.x;   // 0..3
  const int tw = blockIdx.y;   // 0..127
  const int t = tw >> 3, w_ = tw & 7;
  const int ts = tsp[0];
  const int lmin = min(ts + 1, L_SEQ - W_WIN);
  const int lp = min(ts + 1 + t, L_SEQ - W_WIN) + w_ - lmin;
  const unsigned short* E = F + (size_t)lp * (B_SZ * C_CH);
  const unsigned short* P = pred + (size_t)tw * (B_SZ * C_CH);

  const int rowb = bq * 128 + wv * 32;

  // A-fragments: af[tile][kk] = E[rowb + tile*16 + l15][kk*32 + quad*8 ..+8]
  short8 af[2][8];
#pragma unroll
  for (int tile = 0; tile < 2; tile++)
#pragma unroll
    for (int kk = 0; kk < 8; kk++)
      af[tile][kk] =
          *(const short8*)(E + (size_t)(rowb + tile * 16 + l15) * C_CH + kk * 32 + quad * 8);

  float sumr[2][4] = {{0.f, 0.f, 0.f, 0.f}, {0.f, 0.f, 0.f, 0.f}};
  float diag[2][4] = {{0.f, 0.f, 0.f, 0.f}, {0.f, 0.f, 0.f, 0.f}};
  const int chd0 = bq * 8 + wv * 2;  // a-chunk containing the diagonal for tile 0 (tile1: +1)

  short8 bf[2][8];
#pragma unroll
  for (int kk = 0; kk < 8; kk++)
    bf[0][kk] = *(const short8*)(P + (size_t)l15 * C_CH + kk * 32 + quad * 8);

#pragma unroll
  for (int ch = 0; ch < 32; ch++) {
    const int cur = ch & 1, nxt = cur ^ 1;
    if (ch < 31) {
#pragma unroll
      for (int kk = 0; kk < 8; kk++)
        bf[nxt][kk] =
            *(const short8*)(P + (size_t)((ch + 1) * 16 + l15) * C_CH + kk * 32 + quad * 8);
    }
#pragma unroll
    for (int tile = 0; tile < 2; tile++) {
      f32x4 acc = (f32x4){0.f, 0.f, 0.f, 0.f};
#pragma unroll
      for (int kk = 0; kk < 8; kk++)
        acc = __builtin_amdgcn_mfma_f32_16x16x32_bf16(af[tile][kk], bf[cur][kk], acc, 0, 0, 0);
      if (ch == chd0 + tile) {  // wave-uniform branch
#pragma unroll
        for (int r = 0; r < 4; r++)
          if (l15 == quad * 4 + r) diag[tile][r] = acc[r];
      }
#pragma unroll
      for (int r = 0; r < 4; r++) sumr[tile][r] += __expf(acc[r] - NCE_SHIFT);
    }
  }

  // per-row logsumexp + diag -> lane partial
  float lane_nce = 0.f;
#pragma unroll
  for (int tile = 0; tile < 2; tile++)
#pragma unroll
    for (int r = 0; r < 4; r++) {
      float s = sumr[tile][r];
      s += __shfl_xor(s, 1);
      s += __shfl_xor(s, 2);
      s += __shfl_xor(s, 4);
      s += __shfl_xor(s, 8);
      if (l15 == quad * 4 + r) lane_nce += __logf(s) + NCE_SHIFT - diag[tile][r];
    }
  for (int d = 1; d < 64; d <<= 1) lane_nce += __shfl_xor(lane_nce, d);

  __shared__ float wsum[4];
  if (lane == 0) wsum[wv] = lane_nce;
  __syncthreads();
  if (tid == 0) partials[blockIdx.y * 4 + blockIdx.x] = wsum[0] + wsum[1] + wsum[2] + wsum[3];
}

__global__ void nce_finish(const float* __restrict__ partials, float* __restrict__ out) {
  __shared__ float r[256];
  float s = 0.f;
  for (int i = threadIdx.x; i < 512; i += 256) s += partials[i];
  r[threadIdx.x] = s;
  __syncthreads();
  if (threadIdx.x == 0) {
    float tsum = 0.f;
    for (int i = 0; i < 256; i++) tsum += r[i];
    // partials hold sum(lse - diag) = sum(-logp_diag); nce = +sum/N
    out[0] = tsum / 65536.0f;  // B*T*W
  }
}

// ---------------- BN train stats (two stage, fp32) ----------------
__global__ void bn_stage1(const float* __restrict__ h1, float* __restrict__ p1,
                          float* __restrict__ p2) {
  int c = threadIdx.x;  // 128 threads
  int blk = blockIdx.x; // 32 blocks x 128 rows
  float s1 = 0.f, s2 = 0.f;
  for (int r = blk * 128; r < blk * 128 + 128; r++) {
    float v = h1[(size_t)r * 128 + c];
    s1 += v;
    s2 += v * v;
  }
  p1[blk * 128 + c] = s1;
  p2[blk * 128 + c] = s2;
}

__global__ void bn_stage2(const float* __restrict__ p1, const float* __restrict__ p2,
                          const float* __restrict__ g, const float* __restrict__ b,
                          float* __restrict__ sc, float* __restrict__ sh) {
  int c = threadIdx.x;
  float s1 = 0.f, s2 = 0.f;
  for (int k = 0; k < 32; k++) {
    s1 += p1[k * 128 + c];
    s2 += p2[k * 128 + c];
  }
  float mean = s1 * (1.f / 4096.f);
  float var = s2 * (1.f / 4096.f) - mean * mean;  // biased (BN train)
  float scale = g[c] * rsqrtf(var + 1e-5f);
  sc[c] = scale;
  sh[c] = b[c] - mean * scale;
}

// ---------------- BN-apply + ReLU + GEMM2 -> proj (fp32) ----------------
__global__ __launch_bounds__(256) void proj_gemm2(const float* __restrict__ h1,
                                                  const float* __restrict__ sc,
                                                  const float* __restrict__ sh,
                                                  const float* __restrict__ pw2,
                                                  const float* __restrict__ pb2,
                                                  float* __restrict__ out) {
  __shared__ float pw2s[64][129];  // +1 pad breaks bank aliasing
  __shared__ float hs[16][129];
  __shared__ float scs[128], shs[128];
  int tid = threadIdx.x;
  for (int idx = tid; idx < 64 * 128; idx += 256) pw2s[idx >> 7][idx & 127] = pw2[idx];
  if (tid < 128) { scs[tid] = sc[tid]; shs[tid] = sh[tid]; }
  __syncthreads();
  int r0 = blockIdx.x * 64;
  float bb = pb2[tid & 63];
  for (int ch = 0; ch < 4; ch++) {
    int rr0 = r0 + ch * 16;
    for (int idx = tid; idx < 16 * 128; idx += 256) {
      int r = idx >> 7, c = idx & 127;
      float v = h1[(size_t)(rr0 + r) * 128 + c];
      hs[r][c] = fmaxf(v * scs[c] + shs[c], 0.f);
    }
    __syncthreads();
    int oc = tid & 63, og = tid >> 6;
#pragma unroll
    for (int q = 0; q < 4; q++) {
      int row = og * 4 + q;
      float s = bb;
      for (int c = 0; c < 128; c++) s += hs[row][c] * pw2s[oc][c];
      out[(size_t)(rr0 + row) * 64 + oc] = s;
    }
    __syncthreads();
  }
}

extern "C" void kernel_launch(void* const* d_in, const int* in_sizes, int n_in,
                              void* d_out, int out_size, void* d_ws, size_t ws_size,
                              hipStream_t stream) {
  const float* features = (const float*)d_in[0];
  const float* c_t      = (const float*)d_in[1];
  const float* Wk_w     = (const float*)d_in[2];
  const float* Wk_b     = (const float*)d_in[3];
  const float* pw1      = (const float*)d_in[4];
  const float* pb1      = (const float*)d_in[5];
  const float* bn_gamma = (const float*)d_in[6];
  const float* bn_beta  = (const float*)d_in[7];
  const float* pw2      = (const float*)d_in[8];
  const float* pb2      = (const float*)d_in[9];
  const int*   tsp      = (const int*)d_in[10];
  float* out = (float*)d_out;

  // workspace carve-up (~48.2 MB total)
  char* ws = (char*)d_ws;
  size_t off = 0;
  auto carve = [&](size_t bytes) { void* p = ws + off; off += (bytes + 255) & ~(size_t)255; return p; };
  unsigned short* ct_bf  = (unsigned short*)carve((size_t)4096 * 512 * 2);   // c_t bf16 [bw][h]
  unsigned short* wk_bf  = (unsigned short*)carve((size_t)4096 * 512 * 2);   // Wk bf16 [tc][h]
  unsigned short* pw1_bf = (unsigned short*)carve((size_t)128 * 512 * 2);
  unsigned short* F      = (unsigned short*)carve((size_t)NSLAB * 512 * 256 * 2);
  unsigned short* pred   = (unsigned short*)carve((size_t)16 * 8 * 512 * 256 * 2);
  float* h1    = (float*)carve((size_t)4096 * 128 * 4);
  float* bnp1  = (float*)carve((size_t)32 * 128 * 4);
  float* bnp2  = (float*)carve((size_t)32 * 128 * 4);
  float* bnsc  = (float*)carve((size_t)128 * 4);
  float* bnsh  = (float*)carve((size_t)128 * 4);
  float* parts = (float*)carve((size_t)2048 * 4);

  cast_bf<<<2048, 256, 0, stream>>>(c_t, ct_bf, 4096 * 512);
  cast_bf<<<2048, 256, 0, stream>>>(Wk_w, wk_bf, 4096 * 512);
  cast_bf<<<64, 256, 0, stream>>>(pw1, pw1_bf, 128 * 512);
  build_slabs<<<64, 256, 0, stream>>>(features, F, tsp);

  // pred[t][w][a][c] = c_t @ Wk^T + Wk_b   (M=N=4096, K=512)
  gemm_bt<0><<<dim3(32, 32), 256, 0, stream>>>(ct_bf, wk_bf, Wk_b, pred, nullptr, 512);
  // h1 = c_t2d @ pw1^T + pb1   (M=4096, N=128, K=512)
  gemm_bt<1><<<dim3(32, 1), 256, 0, stream>>>(ct_bf, pw1_bf, pb1, nullptr, h1, 512);

  scores_nce2<<<dim3(4, 128), 256, 0, stream>>>(F, pred, tsp, parts);
  nce_finish<<<1, 256, 0, stream>>>(parts, out);

  bn_stage1<<<32, 128, 0, stream>>>(h1, bnp1, bnp2);
  bn_stage2<<<1, 128, 0, stream>>>(bnp1, bnp2, bn_gamma, bn_beta, bnsc, bnsh);
  proj_gemm2<<<64, 256, 0, stream>>>(h1, bnsc, bnsh, pw2, pb2, out + 1);
}

// Round 4
// 378.079 us; speedup vs baseline: 1.7453x; 1.2874x over previous
//
#include <hip/hip_runtime.h>

// Problem constants
#define B_SZ 512
#define C_CH 256
#define L_SEQ 256
#define H_DIM 512
#define T_STEP 16
#define W_WIN 8
#define NSLAB 24   // max distinct l values = T+W-1 = 23, round up

typedef __attribute__((ext_vector_type(8))) short short8;
typedef __attribute__((ext_vector_type(4))) float f32x4;

#define GLOBAL_U32 const __attribute__((address_space(1))) unsigned int*
#define LDS_U32 __attribute__((address_space(3))) unsigned int*
// async 16B/lane global->LDS; LDS dest = wave-uniform base + lane*16
#define ASYNC_COPY16(g, l) \
  __builtin_amdgcn_global_load_lds((GLOBAL_U32)(const void*)(g), (LDS_U32)(void*)(l), 16, 0, 0)

__device__ inline unsigned short f2bf(float x) {  // RNE f32 -> bf16
  unsigned u = __float_as_uint(x);
  u = (u + 0x7FFFu + ((u >> 16) & 1u)) >> 16;
  return (unsigned short)u;
}

// ---------------- cast f32 -> bf16 (4 elems/thread) ----------------
__global__ void cast_bf(const float* __restrict__ s, unsigned short* __restrict__ d, int n) {
  int i = (blockIdx.x * 256 + threadIdx.x) * 4;
  if (i < n) {
    float4 v = ((const float4*)s)[i >> 2];
    ushort4 o;
    o.x = f2bf(v.x); o.y = f2bf(v.y); o.z = f2bf(v.z); o.w = f2bf(v.w);
    ((ushort4*)d)[i >> 2] = o;
  }
}

// ---------------- encode slabs: F[l'][b][c] = bf16(features[b][c][lmin+l']) ----------------
// grid 512 (one block per b), 256 threads (one per c). Per-thread: 24 contiguous
// 4B loads (96B span, L1-resident lines), then 24 wave-coalesced 2B stores
// (lanes cover c -> 128B/wave-inst contiguous).
__global__ __launch_bounds__(256) void build_slabs2(const float* __restrict__ f,
                                                    unsigned short* __restrict__ F,
                                                    const int* __restrict__ tsp) {
  const int ts = tsp[0];
  const int lmin = min(ts + 1, L_SEQ - W_WIN);
  const int b = blockIdx.x;
  const int c = threadIdx.x;
  const float* src = f + ((size_t)b * C_CH + c) * L_SEQ;
  float v[NSLAB];
#pragma unroll
  for (int lp = 0; lp < NSLAB; lp++) {
    int l = lmin + lp;
    v[lp] = (l < L_SEQ) ? src[l] : 0.f;
  }
#pragma unroll
  for (int lp = 0; lp < NSLAB; lp++)
    F[((size_t)lp * B_SZ + b) * C_CH + c] = f2bf(v[lp]);
}

// ---------------- bf16 MFMA GEMM: D = A[M,K] * Bt[N,K]^T + bias[col] ----------------
template <int MODE>
__global__ __launch_bounds__(256) void gemm_bt(const unsigned short* __restrict__ A,
                                               const unsigned short* __restrict__ Bt,
                                               const float* __restrict__ bias,
                                               unsigned short* __restrict__ outb,
                                               float* __restrict__ outf, int K) {
  __shared__ __align__(16) unsigned short As[128 * 64];
  __shared__ __align__(16) unsigned short Bs[128 * 64];
  const int tid = threadIdx.x;
  const int wv = tid >> 6, lane = tid & 63, quad = lane >> 4, l15 = lane & 15;
  const int wm = wv >> 1, wn = wv & 1;
  const int M0 = blockIdx.x * 128, N0 = blockIdx.y * 128;

  f32x4 acc[4][4];
#pragma unroll
  for (int i = 0; i < 4; i++)
#pragma unroll
    for (int j = 0; j < 4; j++) acc[i][j] = (f32x4){0.f, 0.f, 0.f, 0.f};

  for (int k0 = 0; k0 < K; k0 += 64) {
#pragma unroll
    for (int i = 0; i < 4; i++) {
      int chunk = (i * 4 + wv) * 64 + lane;      // 1024 chunks of 16B = [128][64] bf16 tile
      int row = chunk >> 3, off = chunk & 7;     // 8 chunks per 128B row
      const unsigned short* ga = A + (size_t)(M0 + row) * K + k0 + off * 8;
      const unsigned short* gb = Bt + (size_t)(N0 + row) * K + k0 + off * 8;
      ASYNC_COPY16(ga, &As[(size_t)(i * 4 + wv) * 512]);
      ASYNC_COPY16(gb, &Bs[(size_t)(i * 4 + wv) * 512]);
    }
    __syncthreads();  // drains vmcnt
#pragma unroll
    for (int kk = 0; kk < 64; kk += 32) {
      short8 af[4], bfr[4];
#pragma unroll
      for (int i = 0; i < 4; i++)
        af[i] = *(const short8*)&As[(wm * 64 + i * 16 + l15) * 64 + kk + quad * 8];
#pragma unroll
      for (int j = 0; j < 4; j++)
        bfr[j] = *(const short8*)&Bs[(wn * 64 + j * 16 + l15) * 64 + kk + quad * 8];
#pragma unroll
      for (int i = 0; i < 4; i++)
#pragma unroll
        for (int j = 0; j < 4; j++)
          acc[i][j] = __builtin_amdgcn_mfma_f32_16x16x32_bf16(af[i], bfr[j], acc[i][j], 0, 0, 0);
    }
    __syncthreads();
  }

  // epilogue: D mapping col=lane&15, row=quad*4+reg (m89/m91-verified)
#pragma unroll
  for (int i = 0; i < 4; i++) {
    int rbase = M0 + wm * 64 + i * 16 + quad * 4;
#pragma unroll
    for (int j = 0; j < 4; j++) {
      int cc = N0 + wn * 64 + j * 16 + l15;
      float bv = bias[cc];
#pragma unroll
      for (int r = 0; r < 4; r++) {
        int rr = rbase + r;
        float v = acc[i][j][r] + bv;
        if (MODE == 0) {
          int t = cc >> 8, c = cc & 255, a = rr >> 3, w_ = rr & 7;
          outb[((size_t)(t * 8 + w_) * 512 + a) * 256 + c] = f2bf(v);
        } else {
          outf[(size_t)rr * 128 + cc] = v;
        }
      }
    }
  }
}

// ---------------- scores + fixed-shift logsumexp + diag, barrier-free streaming ----------------
// grid (4 b-chunks, 128 tw). Block: 128 b-rows x all 512 a-cols. Wave: 32 rows (2 tiles).
// A-frags (E) register-resident for full K=256; B-frags (P) streamed global->VGPR,
// double-buffered, NO LDS / NO __syncthreads in the loop (fine-grained vmcnt survives).
#define NCE_SHIFT 40.0f
__global__ __launch_bounds__(256, 2) void scores_nce2(const unsigned short* __restrict__ F,
                                                      const unsigned short* __restrict__ pred,
                                                      const int* __restrict__ tsp,
                                                      float* __restrict__ partials) {
  const int tid = threadIdx.x;
  const int wv = tid >> 6, lane = tid & 63, quad = lane >> 4, l15 = lane & 15;
  const int bq = blockIdx.x;   // 0..3
  const int tw = blockIdx.y;   // 0..127
  const int t = tw >> 3, w_ = tw & 7;
  const int ts = tsp[0];
  const int lmin = min(ts + 1, L_SEQ - W_WIN);
  const int lp = min(ts + 1 + t, L_SEQ - W_WIN) + w_ - lmin;
  const unsigned short* E = F + (size_t)lp * (B_SZ * C_CH);
  const unsigned short* P = pred + (size_t)tw * (B_SZ * C_CH);

  const int rowb = bq * 128 + wv * 32;

  // A-fragments: af[tile][kk] = E[rowb + tile*16 + l15][kk*32 + quad*8 ..+8]
  short8 af[2][8];
#pragma unroll
  for (int tile = 0; tile < 2; tile++)
#pragma unroll
    for (int kk = 0; kk < 8; kk++)
      af[tile][kk] =
          *(const short8*)(E + (size_t)(rowb + tile * 16 + l15) * C_CH + kk * 32 + quad * 8);

  float sumr[2][4] = {{0.f, 0.f, 0.f, 0.f}, {0.f, 0.f, 0.f, 0.f}};
  float diag[2][4] = {{0.f, 0.f, 0.f, 0.f}, {0.f, 0.f, 0.f, 0.f}};
  const int chd0 = bq * 8 + wv * 2;  // a-chunk containing the diagonal for tile 0 (tile1: +1)

  short8 bf[2][8];
#pragma unroll
  for (int kk = 0; kk < 8; kk++)
    bf[0][kk] = *(const short8*)(P + (size_t)l15 * C_CH + kk * 32 + quad * 8);

#pragma unroll
  for (int ch = 0; ch < 32; ch++) {
    const int cur = ch & 1, nxt = cur ^ 1;
    if (ch < 31) {
#pragma unroll
      for (int kk = 0; kk < 8; kk++)
        bf[nxt][kk] =
            *(const short8*)(P + (size_t)((ch + 1) * 16 + l15) * C_CH + kk * 32 + quad * 8);
    }
#pragma unroll
    for (int tile = 0; tile < 2; tile++) {
      f32x4 acc = (f32x4){0.f, 0.f, 0.f, 0.f};
#pragma unroll
      for (int kk = 0; kk < 8; kk++)
        acc = __builtin_amdgcn_mfma_f32_16x16x32_bf16(af[tile][kk], bf[cur][kk], acc, 0, 0, 0);
      if (ch == chd0 + tile) {  // wave-uniform branch
#pragma unroll
        for (int r = 0; r < 4; r++)
          if (l15 == quad * 4 + r) diag[tile][r] = acc[r];
      }
#pragma unroll
      for (int r = 0; r < 4; r++) sumr[tile][r] += __expf(acc[r] - NCE_SHIFT);
    }
  }

  // per-row logsumexp + diag -> lane partial
  float lane_nce = 0.f;
#pragma unroll
  for (int tile = 0; tile < 2; tile++)
#pragma unroll
    for (int r = 0; r < 4; r++) {
      float s = sumr[tile][r];
      s += __shfl_xor(s, 1);
      s += __shfl_xor(s, 2);
      s += __shfl_xor(s, 4);
      s += __shfl_xor(s, 8);
      if (l15 == quad * 4 + r) lane_nce += __logf(s) + NCE_SHIFT - diag[tile][r];
    }
  for (int d = 1; d < 64; d <<= 1) lane_nce += __shfl_xor(lane_nce, d);

  __shared__ float wsum[4];
  if (lane == 0) wsum[wv] = lane_nce;
  __syncthreads();
  if (tid == 0) partials[blockIdx.y * 4 + blockIdx.x] = wsum[0] + wsum[1] + wsum[2] + wsum[3];
}

__global__ void nce_finish(const float* __restrict__ partials, float* __restrict__ out) {
  __shared__ float r[256];
  float s = 0.f;
  for (int i = threadIdx.x; i < 512; i += 256) s += partials[i];
  r[threadIdx.x] = s;
  __syncthreads();
  if (threadIdx.x == 0) {
    float tsum = 0.f;
    for (int i = 0; i < 256; i++) tsum += r[i];
    // partials hold sum(lse - diag) = sum(-logp_diag); nce = +sum/N
    out[0] = tsum / 65536.0f;  // B*T*W
  }
}

// ---------------- BN train stats (two stage, fp32) ----------------
__global__ void bn_stage1(const float* __restrict__ h1, float* __restrict__ p1,
                          float* __restrict__ p2) {
  int c = threadIdx.x;  // 128 threads
  int blk = blockIdx.x; // 32 blocks x 128 rows
  float s1 = 0.f, s2 = 0.f;
  for (int r = blk * 128; r < blk * 128 + 128; r++) {
    float v = h1[(size_t)r * 128 + c];
    s1 += v;
    s2 += v * v;
  }
  p1[blk * 128 + c] = s1;
  p2[blk * 128 + c] = s2;
}

__global__ void bn_stage2(const float* __restrict__ p1, const float* __restrict__ p2,
                          const float* __restrict__ g, const float* __restrict__ b,
                          float* __restrict__ sc, float* __restrict__ sh) {
  int c = threadIdx.x;
  float s1 = 0.f, s2 = 0.f;
  for (int k = 0; k < 32; k++) {
    s1 += p1[k * 128 + c];
    s2 += p2[k * 128 + c];
  }
  float mean = s1 * (1.f / 4096.f);
  float var = s2 * (1.f / 4096.f) - mean * mean;  // biased (BN train)
  float scale = g[c] * rsqrtf(var + 1e-5f);
  sc[c] = scale;
  sh[c] = b[c] - mean * scale;
}

// ---------------- BN-apply + ReLU + GEMM2 -> proj (fp32) ----------------
__global__ __launch_bounds__(256) void proj_gemm2(const float* __restrict__ h1,
                                                  const float* __restrict__ sc,
                                                  const float* __restrict__ sh,
                                                  const float* __restrict__ pw2,
                                                  const float* __restrict__ pb2,
                                                  float* __restrict__ out) {
  __shared__ float pw2s[64][129];  // +1 pad breaks bank aliasing
  __shared__ float hs[16][129];
  __shared__ float scs[128], shs[128];
  int tid = threadIdx.x;
  for (int idx = tid; idx < 64 * 128; idx += 256) pw2s[idx >> 7][idx & 127] = pw2[idx];
  if (tid < 128) { scs[tid] = sc[tid]; shs[tid] = sh[tid]; }
  __syncthreads();
  int r0 = blockIdx.x * 64;
  float bb = pb2[tid & 63];
  for (int ch = 0; ch < 4; ch++) {
    int rr0 = r0 + ch * 16;
    for (int idx = tid; idx < 16 * 128; idx += 256) {
      int r = idx >> 7, c = idx & 127;
      float v = h1[(size_t)(rr0 + r) * 128 + c];
      hs[r][c] = fmaxf(v * scs[c] + shs[c], 0.f);
    }
    __syncthreads();
    int oc = tid & 63, og = tid >> 6;
#pragma unroll
    for (int q = 0; q < 4; q++) {
      int row = og * 4 + q;
      float s = bb;
      for (int c = 0; c < 128; c++) s += hs[row][c] * pw2s[oc][c];
      out[(size_t)(rr0 + row) * 64 + oc] = s;
    }
    __syncthreads();
  }
}

extern "C" void kernel_launch(void* const* d_in, const int* in_sizes, int n_in,
                              void* d_out, int out_size, void* d_ws, size_t ws_size,
                              hipStream_t stream) {
  const float* features = (const float*)d_in[0];
  const float* c_t      = (const float*)d_in[1];
  const float* Wk_w     = (const float*)d_in[2];
  const float* Wk_b     = (const float*)d_in[3];
  const float* pw1      = (const float*)d_in[4];
  const float* pb1      = (const float*)d_in[5];
  const float* bn_gamma = (const float*)d_in[6];
  const float* bn_beta  = (const float*)d_in[7];
  const float* pw2      = (const float*)d_in[8];
  const float* pb2      = (const float*)d_in[9];
  const int*   tsp      = (const int*)d_in[10];
  float* out = (float*)d_out;

  // workspace carve-up (~48.2 MB total)
  char* ws = (char*)d_ws;
  size_t off = 0;
  auto carve = [&](size_t bytes) { void* p = ws + off; off += (bytes + 255) & ~(size_t)255; return p; };
  unsigned short* ct_bf  = (unsigned short*)carve((size_t)4096 * 512 * 2);   // c_t bf16 [bw][h]
  unsigned short* wk_bf  = (unsigned short*)carve((size_t)4096 * 512 * 2);   // Wk bf16 [tc][h]
  unsigned short* pw1_bf = (unsigned short*)carve((size_t)128 * 512 * 2);
  unsigned short* F      = (unsigned short*)carve((size_t)NSLAB * 512 * 256 * 2);
  unsigned short* pred   = (unsigned short*)carve((size_t)16 * 8 * 512 * 256 * 2);
  float* h1    = (float*)carve((size_t)4096 * 128 * 4);
  float* bnp1  = (float*)carve((size_t)32 * 128 * 4);
  float* bnp2  = (float*)carve((size_t)32 * 128 * 4);
  float* bnsc  = (float*)carve((size_t)128 * 4);
  float* bnsh  = (float*)carve((size_t)128 * 4);
  float* parts = (float*)carve((size_t)2048 * 4);

  cast_bf<<<2048, 256, 0, stream>>>(c_t, ct_bf, 4096 * 512);
  cast_bf<<<2048, 256, 0, stream>>>(Wk_w, wk_bf, 4096 * 512);
  cast_bf<<<64, 256, 0, stream>>>(pw1, pw1_bf, 128 * 512);
  build_slabs2<<<512, 256, 0, stream>>>(features, F, tsp);

  // pred[t][w][a][c] = c_t @ Wk^T + Wk_b   (M=N=4096, K=512)
  gemm_bt<0><<<dim3(32, 32), 256, 0, stream>>>(ct_bf, wk_bf, Wk_b, pred, nullptr, 512);
  // h1 = c_t2d @ pw1^T + pb1   (M=4096, N=128, K=512)
  gemm_bt<1><<<dim3(32, 1), 256, 0, stream>>>(ct_bf, pw1_bf, pb1, nullptr, h1, 512);

  scores_nce2<<<dim3(4, 128), 256, 0, stream>>>(F, pred, tsp, parts);
  nce_finish<<<1, 256, 0, stream>>>(parts, out);

  bn_stage1<<<32, 128, 0, stream>>>(h1, bnp1, bnp2);
  bn_stage2<<<1, 128, 0, stream>>>(bnp1, bnp2, bn_gamma, bn_beta, bnsc, bnsh);
  proj_gemm2<<<64, 256, 0, stream>>>(h1, bnsc, bnsh, pw2, pb2, out + 1);
}